// Round 15
// baseline (106.792 us; speedup 1.0000x reference)
//
#include <hip/hip_runtime.h>
#include <hip/hip_bf16.h>
#include <cstdint>
#include <cstddef>

// Problem dims
#define NB 2
#define NL 2048
#define NE 1024
#define NH 16
#define ND 64
#define NM (NB * NL)  // 4096 rows total

typedef float f32x4 __attribute__((ext_vector_type(4)));
typedef __bf16 bf16x8 __attribute__((ext_vector_type(8)));
typedef __bf16 bf16x4 __attribute__((ext_vector_type(4)));

#define DEV static __device__ __forceinline__

DEV f32x4 mfma16(bf16x8 a, bf16x8 b, f32x4 c) {
  return __builtin_amdgcn_mfma_f32_16x16x32_bf16(a, b, c, 0, 0, 0);
}

DEV ushort f2bf(float f) {
  uint32_t u = __float_as_uint(f);
  uint32_t r = (u + 0x7fffu + ((u >> 16) & 1u)) >> 16;
  return (ushort)r;
}

#if __has_builtin(__builtin_amdgcn_exp2f)
DEV float fast_exp2(float x) { return __builtin_amdgcn_exp2f(x); }
#else
DEV float fast_exp2(float x) { return exp2f(x); }
#endif

DEV void gl_lds16(const void* src, void* lds_dst) {
  __builtin_amdgcn_global_load_lds(
      (const __attribute__((address_space(1))) void*)src,
      (__attribute__((address_space(3))) void*)lds_dst, 16, 0, 0);
}

// Stage a tile whose rows are 128 bytes (64 bf16) into LDS, linear dest,
// source pre-swizzled with the involution byte ^= ((row&7)<<4) so that
// swizzled ds_read_b128 fragment reads are bank-conflict-reduced.
// 256-thread version: one call covers 4096 B.
template <int NCALLS>
DEV void stage_swz(const char* gbase, size_t row_stride_b, char* lds_base, int tid) {
#pragma unroll
  for (int c = 0; c < NCALLS; ++c) {
    uint32_t P = (uint32_t)(c * 4096 + tid * 16);
    uint32_t r = P >> 7;
    uint32_t Lo = P ^ ((r & 7u) << 4);
    gl_lds16(gbase + (size_t)r * row_stride_b + (Lo & 127u), lds_base + P);
  }
}

// 512-thread version: one call covers 8192 B (64 rows x 128 B).
DEV void stage8k_swz(const char* gbase, size_t row_stride_b, char* lds_base, int tid) {
  uint32_t P = (uint32_t)(tid * 16);
  uint32_t r = P >> 7;
  uint32_t Lo = P ^ ((r & 7u) << 4);
  gl_lds16(gbase + (size_t)r * row_stride_b + (Lo & 127u), lds_base + P);
}

// ---------------------------------------------------------------- pack
__global__ __launch_bounds__(256) void pack_kernel(
    const float* __restrict__ x, const float* __restrict__ wq,
    const float* __restrict__ wk, const float* __restrict__ wv,
    const float* __restrict__ wo, ushort* __restrict__ xb,
    ushort* __restrict__ wqb, ushort* __restrict__ wkb,
    ushort* __restrict__ wvb, ushort* __restrict__ wob) {
  int64_t q = (int64_t)blockIdx.x * 256 + threadIdx.x;  // quad id, 2097152 total
  const float* src;
  ushort* dst;
  bool cl;
  if (q < 1048576) {
    src = x + q * 4;
    dst = xb + q * 4;
    cl = true;
  } else {
    int64_t r = q - 1048576;
    int wsel = (int)(r >> 18);
    int64_t o = (r & 262143) * 4;
    cl = false;
    if (wsel == 0) { src = wq + o; dst = wqb + o; }
    else if (wsel == 1) { src = wk + o; dst = wkb + o; }
    else if (wsel == 2) { src = wv + o; dst = wvb + o; }
    else { src = wo + o; dst = wob + o; }
  }
  float4 v = *(const float4*)src;
  if (cl) {
    v.x = (v.x != v.x) ? 0.f : fminf(fmaxf(v.x, -1e9f), 1e9f);
    v.y = (v.y != v.y) ? 0.f : fminf(fmaxf(v.y, -1e9f), 1e9f);
    v.z = (v.z != v.z) ? 0.f : fminf(fmaxf(v.z, -1e9f), 1e9f);
    v.w = (v.w != v.w) ? 0.f : fminf(fmaxf(v.w, -1e9f), 1e9f);
  }
  ushort4 o4;
  o4.x = f2bf(v.x);
  o4.y = f2bf(v.y);
  o4.z = f2bf(v.z);
  o4.w = f2bf(v.w);
  *(ushort4*)dst = o4;
}

// ---------------------------------------------------------------- QKV GEMM
// C(4096 x 3072) = xb(4096x1024) @ W^T. A double-buffered in LDS (2x16K,
// global_load_lds); B single-buffered (16K) and REG-STAGED (T14): B(t+1)
// issued global->regs right after barrier #1 (lands during compute), written
// ds_write->Bbuf after the next barrier (prev readers done by program order),
// lgkmcnt(0)+cheap barrier #2 before compute. LDS 48K -> 3 blocks/CU so all
// 768 blocks co-reside (was 2/CU + half-empty tail round).
//  Q (pre-scaled by 0.125*log2e) -> (B,H,L,D) ; K -> (B,H,L,D) ; V -> (B,H,D,L)
#define QKV_LOADB(R, t_)                                                      \
  do {                                                                        \
    _Pragma("unroll") for (int c = 0; c < 4; ++c)                             \
        R[c] = *(const bf16x8*)(Bb + (size_t)(brow + 32 * c) * 1024 +         \
                                (t_) * 64 + bcc * 8);                         \
  } while (0)

#define QKV_WRITEB(R)                                                         \
  do {                                                                        \
    _Pragma("unroll") for (int c = 0; c < 4; ++c) {                           \
      uint32_t rr = (uint32_t)(brow + 32 * c);                                \
      uint32_t off = (rr * 128u + (uint32_t)(bcc * 16)) ^ ((rr & 7u) << 4);   \
      *(bf16x8*)(lds + 32768 + off) = R[c];                                   \
    }                                                                         \
  } while (0)

#define QKV_COMP(AB)                                                          \
  do {                                                                        \
    const char* ab = (AB);                                                    \
    const char* bb = lds + 32768;                                             \
    __builtin_amdgcn_s_setprio(1);                                            \
    _Pragma("unroll") for (int kc = 0; kc < 2; ++kc) {                        \
      bf16x8 af[4], bfr[4];                                                   \
      _Pragma("unroll") for (int i = 0; i < 4; ++i) {                         \
        uint32_t ar = (uint32_t)(wm * 64 + i * 16 + ln15);                    \
        uint32_t ao = (ar * 128u + (uint32_t)(kc * 64 + g * 16)) ^            \
                      ((ar & 7u) << 4);                                       \
        af[i] = *(const bf16x8*)(ab + ao);                                    \
        uint32_t br = (uint32_t)(wn * 64 + i * 16 + ln15);                    \
        uint32_t bo_ = (br * 128u + (uint32_t)(kc * 64 + g * 16)) ^           \
                       ((br & 7u) << 4);                                      \
        bfr[i] = *(const bf16x8*)(bb + bo_);                                  \
      }                                                                       \
      _Pragma("unroll") for (int m = 0; m < 4; ++m)                           \
          _Pragma("unroll") for (int n = 0; n < 4; ++n)                       \
              acc[m][n] = mfma16(af[m], bfr[n], acc[m][n]);                   \
    }                                                                         \
    __builtin_amdgcn_s_setprio(0);                                            \
  } while (0)

__global__ __launch_bounds__(256, 3) void qkv_gemm_kernel(
    const ushort* __restrict__ xb, const ushort* __restrict__ wqb,
    const ushort* __restrict__ wkb, const ushort* __restrict__ wvb,
    const float* __restrict__ bq, const float* __restrict__ bk,
    const float* __restrict__ bv, ushort* __restrict__ Qo,
    ushort* __restrict__ Ko, ushort* __restrict__ Vto) {
  __shared__ __align__(128) char lds[49152];  // A dbuf 2x16K | B single 16K
  const int tid = threadIdx.x;
  const int w = tid >> 6, ln = tid & 63;
  const int ln15 = ln & 15, g = ln >> 4;
  const int wm = w >> 1, wn = w & 1;
  const int m0 = blockIdx.y * 128;
  const int which = blockIdx.x >> 3;          // 0=Q 1=K 2=V
  const int n0w = (blockIdx.x & 7) * 128;     // within [0,1024)
  const ushort* Wb = (which == 0) ? wqb : (which == 1) ? wkb : wvb;

  const char* Abase = (const char*)xb + (size_t)m0 * 2048;
  const ushort* Bb = Wb + (size_t)n0w * 1024;  // [128 rows][1024 k], row-major
  const int brow = tid >> 3;  // 0..31 (+32c)
  const int bcc = tid & 7;    // 16B chunk within 64-k slice

  f32x4 acc[4][4];
#pragma unroll
  for (int m = 0; m < 4; ++m)
#pragma unroll
    for (int n = 0; n < 4; ++n) acc[m][n] = {0.f, 0.f, 0.f, 0.f};

  bf16x8 br0[4], br1[4];
  stage_swz<4>(Abase, 2048, lds, tid);
  QKV_LOADB(br0, 0);

  for (int kt = 0; kt < 16; kt += 2) {
    // even step: compute tile kt from Abuf0 + Bbuf
    asm volatile("s_waitcnt vmcnt(0)" ::: "memory");  // A(kt) + B(kt) regs in
    __builtin_amdgcn_s_barrier();  // prev compute done -> Bbuf/Abuf1 free
    asm volatile("" ::: "memory");
    QKV_WRITEB(br0);
    if (kt + 1 < 16) {
      stage_swz<4>(Abase + (kt + 1) * 128, 2048, lds + 16384, tid);
      QKV_LOADB(br1, kt + 1);
    }
    asm volatile("s_waitcnt lgkmcnt(0)" ::: "memory");  // my B writes done
    __builtin_amdgcn_s_barrier();                       // all B writes visible
    asm volatile("" ::: "memory");
    QKV_COMP(lds);
    // odd step: compute tile kt+1 from Abuf1 + Bbuf
    asm volatile("s_waitcnt vmcnt(0)" ::: "memory");
    __builtin_amdgcn_s_barrier();
    asm volatile("" ::: "memory");
    QKV_WRITEB(br1);
    if (kt + 2 < 16) {
      stage_swz<4>(Abase + (kt + 2) * 128, 2048, lds, tid);
      QKV_LOADB(br0, kt + 2);
    }
    asm volatile("s_waitcnt lgkmcnt(0)" ::: "memory");
    __builtin_amdgcn_s_barrier();
    asm volatile("" ::: "memory");
    QKV_COMP(lds + 16384);
  }

  const float* bias = (which == 0) ? bq : (which == 1) ? bk : bv;
  // Q pre-scale: scores use exp2, so fold (1/8)*log2(e) into Q (incl. bias).
  const float sc = (which == 0) ? 0.18033688011112042f : 1.0f;
#pragma unroll
  for (int n = 0; n < 4; ++n) {
    const int col = n0w + wn * 64 + n * 16 + ln15;  // [0,1024)
    const int h = col >> 6, d = col & 63;
    const float bc = bias[col];
#pragma unroll
    for (int m = 0; m < 4; ++m) {
      if (which < 2) {
        ushort* dst = (which == 0) ? Qo : Ko;
#pragma unroll
        for (int j = 0; j < 4; ++j) {
          int mg = m0 + wm * 64 + m * 16 + g * 4 + j;
          int b = mg >> 11, l = mg & 2047;
          dst[((size_t)(b * NH + h) * NL + l) * ND + d] = f2bf((acc[m][n][j] + bc) * sc);
        }
      } else {
        int mg0 = m0 + wm * 64 + m * 16 + g * 4;
        int b = mg0 >> 11, l0 = mg0 & 2047;
        ushort4 pk;
        pk.x = f2bf(acc[m][n][0] + bc);
        pk.y = f2bf(acc[m][n][1] + bc);
        pk.z = f2bf(acc[m][n][2] + bc);
        pk.w = f2bf(acc[m][n][3] + bc);
        *(ushort4*)(Vto + ((size_t)(b * NH + h) * ND + d) * NL + l0) = pk;
      }
    }
  }
}

// ---------------------------------------------------------------- attention
// Causal flash attention, fully-resident balanced grid (R12 proven config).
// 512 blocks x 8 waves (512 thr); block = (bh, 128-row q-tile); wave = 16
// q-rows; KVBLK=64. LDS 48K -> all blocks co-reside. Pair {bx, bx+256} on
// same CU; seg->qt map makes each pair sum to 34 steps. bh = bx&31 keeps
// bh<->XCD L2 affinity. Single barrier per KV step; shfl-free steady-state
// softmax. NOTE (R13 lesson): keep >=4096 waves total — wave-level TLP
// dominates per-wave LDS instruction counts in this latency regime.
__global__ __launch_bounds__(512) void attn_kernel(
    const ushort* __restrict__ Q, const ushort* __restrict__ K,
    const ushort* __restrict__ Vt, ushort* __restrict__ Op) {
  __shared__ __align__(128) char lds[49152];  // K dbuf 16K | V dbuf 16K | P 8x2K
  const int tid = threadIdx.x;
  const int w = tid >> 6, ln = tid & 63;
  const int ln15 = ln & 15, g = ln >> 4;
  const int bx = blockIdx.x;            // [0,512)
  const int bh = bx & 31;               // bh%8 == bx%8 -> stable XCD binding
  const int seg = bx >> 5;              // [0,16)
  const int qt = (seg < 8) ? 15 - seg : seg - 8;  // pair {s,s+8} sums to 34
  const int nt = 2 * qt + 2;            // KV tiles of 64

  const int b = bh >> 4, h = bh & 15;
  const ushort* Qh = Q + (size_t)bh * NL * ND;
  const ushort* Kh = K + (size_t)bh * NL * ND;
  const ushort* Vth = Vt + (size_t)bh * ND * NL;
  const uint32_t pbase = 32768u + (uint32_t)w * 2048u;

  const int q0 = qt * 128;
  const int r0 = q0 + w * 16;  // this wave's first q row

  bf16x8 qf[2];
#pragma unroll
  for (int kc = 0; kc < 2; ++kc)
    qf[kc] = *(const bf16x8*)(Qh + (size_t)(r0 + ln15) * ND + kc * 32 + g * 8);

  f32x4 o_acc[4];
#pragma unroll
  for (int n = 0; n < 4; ++n) o_acc[n] = {0.f, 0.f, 0.f, 0.f};
  float m_run = -1e30f, l_run = 0.f;  // per-lane; l_run is a g-partial sum

  int cur = 0;
  stage8k_swz((const char*)Kh, 128, lds, tid);
  stage8k_swz((const char*)Vth, (size_t)NL * 2, lds + 16384, tid);

  for (int t = 0; t < nt; ++t) {
    const int s0 = t * 64;
    // tile t's loads were issued a full step ago -> this drain is cheap
    asm volatile("s_waitcnt vmcnt(0)" ::: "memory");
    __builtin_amdgcn_s_barrier();  // tile t visible; prev-buf reads all done
    asm volatile("" ::: "memory");
    if (t + 1 < nt) {  // stage next tile into the buffer just freed
      stage8k_swz((const char*)Kh + (size_t)(s0 + 64) * 128, 128,
                  lds + (cur ^ 1) * 8192, tid);
      stage8k_swz((const char*)Vth + (size_t)(s0 + 64) * 2, (size_t)NL * 2,
                  lds + 16384 + (cur ^ 1) * 8192, tid);
    }

    // wave-uniform: this wave's rows are entirely before the tile -> skip
    if (s0 <= r0 + 15) {
      const char* kb = lds + cur * 8192;
      const char* vb = lds + 16384 + cur * 8192;

      // S^T = K Q^T : s_acc[n][j] holds k = s0+n*16+g*4+j, q = r0+ln15
      f32x4 s_acc[4];
#pragma unroll
      for (int n = 0; n < 4; ++n) s_acc[n] = {0.f, 0.f, 0.f, 0.f};
      __builtin_amdgcn_s_setprio(1);
#pragma unroll
      for (int kc = 0; kc < 2; ++kc) {
        bf16x8 kf[4];
#pragma unroll
        for (int n = 0; n < 4; ++n) {
          uint32_t kr = (uint32_t)(n * 16 + ln15);
          uint32_t off = (kr * 128u + (uint32_t)(kc * 64 + g * 16)) ^ ((kr & 7u) << 4);
          kf[n] = *(const bf16x8*)(kb + off);
        }
#pragma unroll
        for (int n = 0; n < 4; ++n) s_acc[n] = mfma16(kf[n], qf[kc], s_acc[n]);
      }
      __builtin_amdgcn_s_setprio(0);

      // causal mask on boundary tiles (wave-uniform test)
      if (s0 + 63 > r0) {
        const int qi = r0 + ln15;
#pragma unroll
        for (int n = 0; n < 4; ++n)
#pragma unroll
          for (int j = 0; j < 4; ++j) {
            int si = s0 + n * 16 + g * 4 + j;
            s_acc[n][j] = (si > qi) ? -1e30f : s_acc[n][j];
          }
      }

      // softmax: lane-local max tree (no shfl); rescale branch is rare.
      float mx;
      {
        float a0 = fmaxf(fmaxf(s_acc[0][0], s_acc[0][1]), s_acc[0][2]);
        float a1 = fmaxf(fmaxf(s_acc[0][3], s_acc[1][0]), s_acc[1][1]);
        float a2 = fmaxf(fmaxf(s_acc[1][2], s_acc[1][3]), s_acc[2][0]);
        float a3 = fmaxf(fmaxf(s_acc[2][1], s_acc[2][2]), s_acc[2][3]);
        float a4 = fmaxf(fmaxf(s_acc[3][0], s_acc[3][1]), s_acc[3][2]);
        float b0 = fmaxf(fmaxf(a0, a1), a2);
        float b1 = fmaxf(fmaxf(a3, a4), s_acc[3][3]);
        mx = fmaxf(b0, b1);
      }
      if (__any(mx > m_run + 8.0f)) {  // defer-max: P bounded by 2^8
        float mr = fmaxf(mx, __shfl_xor(mx, 16));
        mr = fmaxf(mr, __shfl_xor(mr, 32));     // row max, uniform across g
        float mn = fmaxf(m_run, mr);
        float al = fast_exp2(m_run - mn);       // row-uniform
        m_run = mn;
        l_run *= al;
#pragma unroll
        for (int j = 0; j < 4; ++j) {
          float aj = __shfl(al, g * 4 + j);  // alpha of q-row g*4+j
#pragma unroll
          for (int n = 0; n < 4; ++n) o_acc[n][j] *= aj;
        }
      }
      float ps = 0.f;
#pragma unroll
      for (int n = 0; n < 4; ++n) {
        float p0 = fast_exp2(s_acc[n][0] - m_run);
        float p1 = fast_exp2(s_acc[n][1] - m_run);
        float p2 = fast_exp2(s_acc[n][2] - m_run);
        float p3 = fast_exp2(s_acc[n][3] - m_run);
        ps += (p0 + p1) + (p2 + p3);
        bf16x4 pk = {(__bf16)p0, (__bf16)p1, (__bf16)p2, (__bf16)p3};
        // P[q=ln15][k=n*16+g*4 .. +3], row-swizzled like K/V
        uint32_t off = ((uint32_t)ln15 * 128u + (uint32_t)(n * 32 + g * 8)) ^
                       (((uint32_t)ln15 & 7u) << 4);
        *(bf16x4*)(lds + pbase + off) = pk;
      }
      l_run += ps;  // g-partial; reduced once in the epilogue

      // O += P V  (P wave-private)
      __builtin_amdgcn_s_setprio(1);
#pragma unroll
      for (int kc = 0; kc < 2; ++kc) {
        uint32_t poff = ((uint32_t)ln15 * 128u + (uint32_t)(kc * 64 + g * 16)) ^
                        (((uint32_t)ln15 & 7u) << 4);
        bf16x8 pf = *(const bf16x8*)(lds + pbase + poff);
        bf16x8 vf[4];
#pragma unroll
        for (int n = 0; n < 4; ++n) {
          uint32_t vr = (uint32_t)(n * 16 + ln15);
          uint32_t off = (vr * 128u + (uint32_t)(kc * 64 + g * 16)) ^ ((vr & 7u) << 4);
          vf[n] = *(const bf16x8*)(vb + off);
        }
#pragma unroll
        for (int n = 0; n < 4; ++n) o_acc[n] = mfma16(pf, vf[n], o_acc[n]);
      }
      __builtin_amdgcn_s_setprio(0);
    }
    cur ^= 1;  // single barrier per step: next iter's barrier covers reuse
  }

  // complete the deferred cross-g l reduction (butterfly over bits 4,5)
  l_run += __shfl_xor(l_run, 16);
  l_run += __shfl_xor(l_run, 32);

  // normalize and write final O (bf16) packed as (B*L, E)
  float invl = 1.0f / l_run;
#pragma unroll
  for (int j = 0; j < 4; ++j) {
    float inv = __shfl(invl, g * 4 + j);
    int qi = r0 + g * 4 + j;
    size_t rowo = ((size_t)b * NL + qi) * NE + h * ND;
#pragma unroll
    for (int n = 0; n < 4; ++n) Op[rowo + n * 16 + ln15] = f2bf(o_acc[n][j] * inv);
  }
}

// ---------------------------------------------------------------- out-proj + residual
// Double-buffered LDS, single barrier per K-step (same as R11 qkv).
__global__ __launch_bounds__(256) void oproj_kernel(
    const ushort* __restrict__ ob, const ushort* __restrict__ wob,
    const float* __restrict__ bo, const float* __restrict__ x,
    float* __restrict__ out) {
  __shared__ __align__(128) char lds[65536];  // A dbuf 2x16K | B dbuf 2x16K
  const int tid = threadIdx.x;
  const int w = tid >> 6, ln = tid & 63;
  const int ln15 = ln & 15, g = ln >> 4;
  const int wm = w >> 1, wn = w & 1;
  const int m0 = blockIdx.y * 128;
  const int n0 = blockIdx.x * 128;

  const char* Abase = (const char*)ob + (size_t)m0 * 2048;
  const char* Bbase = (const char*)wob + (size_t)n0 * 2048;

  f32x4 acc[4][4];
#pragma unroll
  for (int m = 0; m < 4; ++m)
#pragma unroll
    for (int n = 0; n < 4; ++n) acc[m][n] = {0.f, 0.f, 0.f, 0.f};

  int cur = 0;
  stage_swz<4>(Abase, 2048, lds, tid);
  stage_swz<4>(Bbase, 2048, lds + 32768, tid);

  for (int kt = 0; kt < 16; ++kt) {
    asm volatile("s_waitcnt vmcnt(0)" ::: "memory");
    __builtin_amdgcn_s_barrier();
    asm volatile("" ::: "memory");
    if (kt + 1 < 16) {
      stage_swz<4>(Abase + (kt + 1) * 128, 2048, lds + (cur ^ 1) * 16384, tid);
      stage_swz<4>(Bbase + (kt + 1) * 128, 2048,
                   lds + 32768 + (cur ^ 1) * 16384, tid);
    }
    const char* ab = lds + cur * 16384;
    const char* bb = lds + 32768 + cur * 16384;
    __builtin_amdgcn_s_setprio(1);
#pragma unroll
    for (int kc = 0; kc < 2; ++kc) {
      bf16x8 af[4], bfr[4];
#pragma unroll
      for (int i = 0; i < 4; ++i) {
        uint32_t ar = (uint32_t)(wm * 64 + i * 16 + ln15);
        uint32_t ao = (ar * 128u + (uint32_t)(kc * 64 + g * 16)) ^ ((ar & 7u) << 4);
        af[i] = *(const bf16x8*)(ab + ao);
        uint32_t br = (uint32_t)(wn * 64 + i * 16 + ln15);
        uint32_t bo_ = (br * 128u + (uint32_t)(kc * 64 + g * 16)) ^ ((br & 7u) << 4);
        bfr[i] = *(const bf16x8*)(bb + bo_);
      }
#pragma unroll
      for (int m = 0; m < 4; ++m)
#pragma unroll
        for (int n = 0; n < 4; ++n) acc[m][n] = mfma16(af[m], bfr[n], acc[m][n]);
    }
    __builtin_amdgcn_s_setprio(0);
    cur ^= 1;
  }

#pragma unroll
  for (int n = 0; n < 4; ++n) {
    const int col = n0 + wn * 64 + n * 16 + ln15;
    const float bc = bo[col];
#pragma unroll
    for (int m = 0; m < 4; ++m)
#pragma unroll
      for (int j = 0; j < 4; ++j) {
        int mg = m0 + wm * 64 + m * 16 + g * 4 + j;
        size_t idx = (size_t)mg * NE + col;
        out[idx] = acc[m][n][j] + bc + x[idx];
      }
  }
}

// ---------------------------------------------------------------- LayerNorm (in-place)
__global__ __launch_bounds__(256) void ln_kernel(float* __restrict__ io,
                                                 const float* __restrict__ gamma,
                                                 const float* __restrict__ beta) {
  const int row = blockIdx.x, tid = threadIdx.x;
  const int w = tid >> 6, ln = tid & 63;
  float4 v = *(const float4*)(io + (size_t)row * NE + tid * 4);
  float s = v.x + v.y + v.z + v.w;
  float ss = v.x * v.x + v.y * v.y + v.z * v.z + v.w * v.w;
#pragma unroll
  for (int d = 1; d < 64; d <<= 1) {
    s += __shfl_xor(s, d);
    ss += __shfl_xor(ss, d);
  }
  __shared__ float red[8];
  if (ln == 0) {
    red[w] = s;
    red[4 + w] = ss;
  }
  __syncthreads();
  s = red[0] + red[1] + red[2] + red[3];
  ss = red[4] + red[5] + red[6] + red[7];
  const float mu = s * (1.0f / (float)NE);
  float var = ss * (1.0f / (float)NE) - mu * mu;
  const float inv = rsqrtf(var + 1e-5f);
  float4 gv = *(const float4*)(gamma + tid * 4);
  float4 bv = *(const float4*)(beta + tid * 4);
  float4 o;
  o.x = (v.x - mu) * inv * gv.x + bv.x;
  o.y = (v.y - mu) * inv * gv.y + bv.y;
  o.z = (v.z - mu) * inv * gv.z + bv.z;
  o.w = (v.w - mu) * inv * gv.w + bv.w;
  *(float4*)(io + (size_t)row * NE + tid * 4) = o;
}

// ---------------------------------------------------------------- launch
extern "C" void kernel_launch(void* const* d_in, const int* in_sizes, int n_in,
                              void* d_out, int out_size, void* d_ws, size_t ws_size,
                              hipStream_t stream) {
  const float* x = (const float*)d_in[0];
  // d_in[1] = mask (causal, recomputed analytically -> unused)
  const float* Wq = (const float*)d_in[2];
  const float* bq = (const float*)d_in[3];
  const float* Wk = (const float*)d_in[4];
  const float* bk = (const float*)d_in[5];
  const float* Wv = (const float*)d_in[6];
  const float* bv = (const float*)d_in[7];
  const float* Wo = (const float*)d_in[8];
  const float* bo = (const float*)d_in[9];
  const float* gamma = (const float*)d_in[10];
  const float* beta = (const float*)d_in[11];

  char* ws = (char*)d_ws;
  ushort* xb  = (ushort*)(ws + 0);          // 8 MB  (4096x1024 bf16)
  ushort* wqb = (ushort*)(ws + 8388608);    // 2 MB
  ushort* wkb = (ushort*)(ws + 10485760);   // 2 MB
  ushort* wvb = (ushort*)(ws + 12582912);   // 2 MB
  ushort* wob = (ushort*)(ws + 14680064);   // 2 MB
  ushort* Qb  = (ushort*)(ws + 16777216);   // 8 MB (B,H,L,D) pre-scaled
  ushort* Kb  = (ushort*)(ws + 25165824);   // 8 MB (B,H,L,D)
  ushort* Vtb = (ushort*)(ws + 33554432);   // 8 MB (B,H,D,L)
  ushort* Ob  = (ushort*)(ws + 41943040);   // 8 MB (B*L, E)

  pack_kernel<<<8192, 256, 0, stream>>>(x, Wq, Wk, Wv, Wo, xb, wqb, wkb, wvb, wob);
  qkv_gemm_kernel<<<dim3(24, 32), 256, 0, stream>>>(xb, wqb, wkb, wvb, bq, bk, bv,
                                                    Qb, Kb, Vtb);
  attn_kernel<<<512, 512, 0, stream>>>(Qb, Kb, Vtb, Ob);
  oproj_kernel<<<dim3(8, 32), 256, 0, stream>>>(Ob, wob, bo, x, (float*)d_out);
  ln_kernel<<<4096, 256, 0, stream>>>((float*)d_out, gamma, beta);
}

// Round 17
// 103.111 us; speedup vs baseline: 1.0357x; 1.0357x over previous
//
#include <hip/hip_runtime.h>
#include <hip/hip_bf16.h>
#include <cstdint>
#include <cstddef>

// Problem dims
#define NB 2
#define NL 2048
#define NE 1024
#define NH 16
#define ND 64
#define NM (NB * NL)  // 4096 rows total

typedef float f32x4 __attribute__((ext_vector_type(4)));
typedef __bf16 bf16x8 __attribute__((ext_vector_type(8)));
typedef __bf16 bf16x4 __attribute__((ext_vector_type(4)));

#define DEV static __device__ __forceinline__

DEV f32x4 mfma16(bf16x8 a, bf16x8 b, f32x4 c) {
  return __builtin_amdgcn_mfma_f32_16x16x32_bf16(a, b, c, 0, 0, 0);
}

DEV ushort f2bf(float f) {
  uint32_t u = __float_as_uint(f);
  uint32_t r = (u + 0x7fffu + ((u >> 16) & 1u)) >> 16;
  return (ushort)r;
}

#if __has_builtin(__builtin_amdgcn_exp2f)
DEV float fast_exp2(float x) { return __builtin_amdgcn_exp2f(x); }
#else
DEV float fast_exp2(float x) { return exp2f(x); }
#endif

DEV void gl_lds16(const void* src, void* lds_dst) {
  __builtin_amdgcn_global_load_lds(
      (const __attribute__((address_space(1))) void*)src,
      (__attribute__((address_space(3))) void*)lds_dst, 16, 0, 0);
}

// Stage a tile whose rows are 128 bytes (64 bf16) into LDS, linear dest,
// source pre-swizzled with the involution byte ^= ((row&7)<<4).
// 256-thread version: one call covers 4096 B.
template <int NCALLS>
DEV void stage_swz(const char* gbase, size_t row_stride_b, char* lds_base, int tid) {
#pragma unroll
  for (int c = 0; c < NCALLS; ++c) {
    uint32_t P = (uint32_t)(c * 4096 + tid * 16);
    uint32_t r = P >> 7;
    uint32_t Lo = P ^ ((r & 7u) << 4);
    gl_lds16(gbase + (size_t)r * row_stride_b + (Lo & 127u), lds_base + P);
  }
}

// 512-thread version: one call covers 8192 B (64 rows x 128 B).
DEV void stage8k_swz(const char* gbase, size_t row_stride_b, char* lds_base, int tid) {
  uint32_t P = (uint32_t)(tid * 16);
  uint32_t r = P >> 7;
  uint32_t Lo = P ^ ((r & 7u) << 4);
  gl_lds16(gbase + (size_t)r * row_stride_b + (Lo & 127u), lds_base + P);
}

// 512-thread, one 8KB chunk (64 rows) at chunk index c of a row-major tile.
DEV void stage_chunk(const char* gbase, size_t row_stride_b, char* lds_base,
                     int tid, int c) {
  uint32_t P = (uint32_t)(c * 8192 + tid * 16);
  uint32_t r = P >> 7;
  uint32_t Lo = P ^ ((r & 7u) << 4);
  gl_lds16(gbase + (size_t)r * row_stride_b + (Lo & 127u), lds_base + P);
}

// ---------------------------------------------------------------- pack
__global__ __launch_bounds__(256) void pack_kernel(
    const float* __restrict__ x, const float* __restrict__ wq,
    const float* __restrict__ wk, const float* __restrict__ wv,
    const float* __restrict__ wo, ushort* __restrict__ xb,
    ushort* __restrict__ wqb, ushort* __restrict__ wkb,
    ushort* __restrict__ wvb, ushort* __restrict__ wob) {
  int64_t q = (int64_t)blockIdx.x * 256 + threadIdx.x;  // quad id, 2097152 total
  const float* src;
  ushort* dst;
  bool cl;
  if (q < 1048576) {
    src = x + q * 4;
    dst = xb + q * 4;
    cl = true;
  } else {
    int64_t r = q - 1048576;
    int wsel = (int)(r >> 18);
    int64_t o = (r & 262143) * 4;
    cl = false;
    if (wsel == 0) { src = wq + o; dst = wqb + o; }
    else if (wsel == 1) { src = wk + o; dst = wkb + o; }
    else if (wsel == 2) { src = wv + o; dst = wvb + o; }
    else { src = wo + o; dst = wob + o; }
  }
  float4 v = *(const float4*)src;
  if (cl) {
    v.x = (v.x != v.x) ? 0.f : fminf(fmaxf(v.x, -1e9f), 1e9f);
    v.y = (v.y != v.y) ? 0.f : fminf(fmaxf(v.y, -1e9f), 1e9f);
    v.z = (v.z != v.z) ? 0.f : fminf(fmaxf(v.z, -1e9f), 1e9f);
    v.w = (v.w != v.w) ? 0.f : fminf(fmaxf(v.w, -1e9f), 1e9f);
  }
  ushort4 o4;
  o4.x = f2bf(v.x);
  o4.y = f2bf(v.y);
  o4.z = f2bf(v.z);
  o4.w = f2bf(v.w);
  *(ushort4*)dst = o4;
}

// ---------------------------------------------------------------- QKV GEMM
// Fused C[4096][3072] = xb @ [Wq;Wk;Wv]^T (wqb/wkb/wvb contiguous in ws).
// 256x192 tile, 8 waves (512 thr), per-wave out 128x48, BK=64. LDS: A dbuf
// 2x32K + B dbuf 2x24K = 112K, 1 block/CU, grid 256 = zero tail. Per K-tile:
// ONE {vmcnt(0); barrier}; B-frags -> regs (B LDS dead after); 4 phases:
// {stage chunk(s) of tile t+1 into other dbuf (freed a full tile ago),
//  prefetch next A-frags, lgkmcnt+sched_barrier, 12 MFMA @ setprio(1)}.
// Rationale (R15 post-mortem): 128^2 structure is LDS-BW bound; this doubles
// FLOP per LDS byte -> MFMA-bound.
__global__ __launch_bounds__(512) void qkv_gemm_kernel(
    const ushort* __restrict__ xb, const ushort* __restrict__ wqkv,
    const float* __restrict__ bq, const float* __restrict__ bk,
    const float* __restrict__ bv, ushort* __restrict__ Qo,
    ushort* __restrict__ Ko, ushort* __restrict__ Vto) {
  __shared__ __align__(128) char lds[114688];  // A 2x32K at 0; B 2x24K at 65536
  const int tid = threadIdx.x;
  const int ln = tid & 63;
  const int ln15 = ln & 15, g = ln >> 4;
  const int wid = tid >> 6;
  const int wr = wid >> 2, wc = wid & 3;  // wave out: rows wr*128+, cols wc*48+
  const int mt_ = blockIdx.x >> 4, nt_ = blockIdx.x & 15;
  const int m0 = mt_ * 256, n0 = nt_ * 192;

  const char* Abase = (const char*)xb + (size_t)m0 * 2048;
  const char* Bbase = (const char*)wqkv + (size_t)n0 * 2048;

  f32x4 acc[8][3];
#pragma unroll
  for (int mi = 0; mi < 8; ++mi)
#pragma unroll
    for (int ni = 0; ni < 3; ++ni) acc[mi][ni] = {0.f, 0.f, 0.f, 0.f};

  // prologue: stage tile 0 into dbuf0 (A 4 chunks + B 3 chunks)
  stage_chunk(Abase, 2048, lds, tid, 0);
  stage_chunk(Abase, 2048, lds, tid, 1);
  stage_chunk(Abase, 2048, lds, tid, 2);
  stage_chunk(Abase, 2048, lds, tid, 3);
  stage_chunk(Bbase, 2048, lds + 65536, tid, 0);
  stage_chunk(Bbase, 2048, lds + 65536, tid, 1);
  stage_chunk(Bbase, 2048, lds + 65536, tid, 2);

  for (int kt = 0; kt < 16; ++kt) {
    asm volatile("s_waitcnt vmcnt(0)" ::: "memory");  // tile kt landed
    __builtin_amdgcn_s_barrier();  // all waves done with this dbuf's old tile
    asm volatile("" ::: "memory");
    const char* ab = lds + (kt & 1) * 32768;
    const char* bb = lds + 65536 + (kt & 1) * 24576;
    const char* anx = Abase + (kt + 1) * 128;
    const char* bnx = Bbase + (kt + 1) * 128;
    char* a_dst = lds + ((kt + 1) & 1) * 32768;
    char* b_dst = lds + 65536 + ((kt + 1) & 1) * 24576;

    // B fragments -> regs (B LDS dead afterwards)
    bf16x8 bfr[2][3];
#pragma unroll
    for (int kc = 0; kc < 2; ++kc)
#pragma unroll
      for (int ni = 0; ni < 3; ++ni) {
        uint32_t br = (uint32_t)(wc * 48 + ni * 16 + ln15);
        uint32_t off = (br * 128u + (uint32_t)(kc * 64 + g * 16)) ^ ((br & 7u) << 4);
        bfr[kc][ni] = *(const bf16x8*)(bb + off);
      }
    // A fragments for phase 0
    bf16x8 afA[2][2], afB[2][2];
#pragma unroll
    for (int mi2 = 0; mi2 < 2; ++mi2)
#pragma unroll
      for (int kc = 0; kc < 2; ++kc) {
        uint32_t ar = (uint32_t)(wr * 128 + mi2 * 16 + ln15);
        uint32_t off = (ar * 128u + (uint32_t)(kc * 64 + g * 16)) ^ ((ar & 7u) << 4);
        afA[mi2][kc] = *(const bf16x8*)(ab + off);
      }

#pragma unroll
    for (int p = 0; p < 4; ++p) {
      // stage tile kt+1 chunk(s): p0:A01 p1:A23 p2:B01 p3:B2
      if (kt + 1 < 16) {
        if (p == 0) { stage_chunk(anx, 2048, a_dst, tid, 0);
                      stage_chunk(anx, 2048, a_dst, tid, 1); }
        else if (p == 1) { stage_chunk(anx, 2048, a_dst, tid, 2);
                           stage_chunk(anx, 2048, a_dst, tid, 3); }
        else if (p == 2) { stage_chunk(bnx, 2048, b_dst, tid, 0);
                           stage_chunk(bnx, 2048, b_dst, tid, 1); }
        else { stage_chunk(bnx, 2048, b_dst, tid, 2); }
      }
      // prefetch next phase's A frags into the other reg buffer
      if (p < 3) {
#pragma unroll
        for (int mi2 = 0; mi2 < 2; ++mi2)
#pragma unroll
          for (int kc = 0; kc < 2; ++kc) {
            uint32_t ar = (uint32_t)(wr * 128 + (2 * (p + 1) + mi2) * 16 + ln15);
            uint32_t off = (ar * 128u + (uint32_t)(kc * 64 + g * 16)) ^
                           ((ar & 7u) << 4);
            if (p & 1) afA[mi2][kc] = *(const bf16x8*)(ab + off);
            else       afB[mi2][kc] = *(const bf16x8*)(ab + off);
          }
        asm volatile("s_waitcnt lgkmcnt(4)" ::: "memory");
      } else {
        asm volatile("s_waitcnt lgkmcnt(0)" ::: "memory");
      }
      __builtin_amdgcn_sched_barrier(0);  // rule 18: fence MFMA past lgkmcnt
      __builtin_amdgcn_s_setprio(1);
#pragma unroll
      for (int ni = 0; ni < 3; ++ni)
#pragma unroll
        for (int kc = 0; kc < 2; ++kc)
#pragma unroll
          for (int mi2 = 0; mi2 < 2; ++mi2) {
            if (p & 1)
              acc[2 * p + mi2][ni] = mfma16(afB[mi2][kc], bfr[kc][ni],
                                            acc[2 * p + mi2][ni]);
            else
              acc[2 * p + mi2][ni] = mfma16(afA[mi2][kc], bfr[kc][ni],
                                            acc[2 * p + mi2][ni]);
          }
      __builtin_amdgcn_s_setprio(0);
    }
  }

  // epilogue: scatter with per-column which/bias/scale
#pragma unroll
  for (int ni = 0; ni < 3; ++ni) {
    const int col = n0 + wc * 48 + ni * 16 + ln15;  // [0,3072)
    const int which = col >> 10;                    // 0=Q 1=K 2=V
    const int cw = col & 1023;
    const int h = cw >> 6, d = cw & 63;
    const float bc = (which == 0) ? bq[cw] : (which == 1) ? bk[cw] : bv[cw];
    const float sc = (which == 0) ? 0.18033688011112042f : 1.0f;
#pragma unroll
    for (int mi = 0; mi < 8; ++mi) {
      if (which < 2) {
        ushort* dst = (which == 0) ? Qo : Ko;
#pragma unroll
        for (int j = 0; j < 4; ++j) {
          int mg = m0 + wr * 128 + mi * 16 + g * 4 + j;
          int b = mg >> 11, l = mg & 2047;
          dst[((size_t)(b * NH + h) * NL + l) * ND + d] =
              f2bf((acc[mi][ni][j] + bc) * sc);
        }
      } else {
        int mg0 = m0 + wr * 128 + mi * 16 + g * 4;
        int b = mg0 >> 11, l0 = mg0 & 2047;
        ushort4 pk;
        pk.x = f2bf(acc[mi][ni][0] + bc);
        pk.y = f2bf(acc[mi][ni][1] + bc);
        pk.z = f2bf(acc[mi][ni][2] + bc);
        pk.w = f2bf(acc[mi][ni][3] + bc);
        *(ushort4*)(Vto + ((size_t)(b * NH + h) * ND + d) * NL + l0) = pk;
      }
    }
  }
}

// ---------------------------------------------------------------- attention
// Causal flash attention, fully-resident balanced grid (R12 proven config).
// 512 blocks x 8 waves (512 thr); block = (bh, 128-row q-tile); wave = 16
// q-rows; KVBLK=64. LDS 48K -> all blocks co-reside. Pair {bx, bx+256} on
// same CU; seg->qt map makes each pair sum to 34 steps. bh = bx&31 keeps
// bh<->XCD L2 affinity. Single barrier per KV step; shfl-free steady-state
// softmax. (R13 lesson: keep >=4096 waves total.)
__global__ __launch_bounds__(512) void attn_kernel(
    const ushort* __restrict__ Q, const ushort* __restrict__ K,
    const ushort* __restrict__ Vt, ushort* __restrict__ Op) {
  __shared__ __align__(128) char lds[49152];  // K dbuf 16K, V dbuf 16K, P 8x2K
  const int tid = threadIdx.x;
  const int w = tid >> 6, ln = tid & 63;
  const int ln15 = ln & 15, g = ln >> 4;
  const int bx = blockIdx.x;            // [0,512)
  const int bh = bx & 31;               // bh%8 == bx%8 -> stable XCD binding
  const int seg = bx >> 5;              // [0,16)
  const int qt = (seg < 8) ? 15 - seg : seg - 8;  // pair {s,s+8} sums to 34
  const int nt = 2 * qt + 2;            // KV tiles of 64

  const int b = bh >> 4, h = bh & 15;
  const ushort* Qh = Q + (size_t)bh * NL * ND;
  const ushort* Kh = K + (size_t)bh * NL * ND;
  const ushort* Vth = Vt + (size_t)bh * ND * NL;
  const uint32_t pbase = 32768u + (uint32_t)w * 2048u;

  const int q0 = qt * 128;
  const int r0 = q0 + w * 16;  // this wave's first q row

  bf16x8 qf[2];
#pragma unroll
  for (int kc = 0; kc < 2; ++kc)
    qf[kc] = *(const bf16x8*)(Qh + (size_t)(r0 + ln15) * ND + kc * 32 + g * 8);

  f32x4 o_acc[4];
#pragma unroll
  for (int n = 0; n < 4; ++n) o_acc[n] = {0.f, 0.f, 0.f, 0.f};
  float m_run = -1e30f, l_run = 0.f;  // per-lane; l_run is a g-partial sum

  int cur = 0;
  stage8k_swz((const char*)Kh, 128, lds, tid);
  stage8k_swz((const char*)Vth, (size_t)NL * 2, lds + 16384, tid);

  for (int t = 0; t < nt; ++t) {
    const int s0 = t * 64;
    asm volatile("s_waitcnt vmcnt(0)" ::: "memory");
    __builtin_amdgcn_s_barrier();  // tile t visible; prev-buf reads all done
    asm volatile("" ::: "memory");
    if (t + 1 < nt) {  // stage next tile into the buffer just freed
      stage8k_swz((const char*)Kh + (size_t)(s0 + 64) * 128, 128,
                  lds + (cur ^ 1) * 8192, tid);
      stage8k_swz((const char*)Vth + (size_t)(s0 + 64) * 2, (size_t)NL * 2,
                  lds + 16384 + (cur ^ 1) * 8192, tid);
    }

    // wave-uniform: this wave's rows are entirely before the tile -> skip
    if (s0 <= r0 + 15) {
      const char* kb = lds + cur * 8192;
      const char* vb = lds + 16384 + cur * 8192;

      // S^T = K Q^T : s_acc[n][j] holds k = s0+n*16+g*4+j, q = r0+ln15
      f32x4 s_acc[4];
#pragma unroll
      for (int n = 0; n < 4; ++n) s_acc[n] = {0.f, 0.f, 0.f, 0.f};
      __builtin_amdgcn_s_setprio(1);
#pragma unroll
      for (int kc = 0; kc < 2; ++kc) {
        bf16x8 kf[4];
#pragma unroll
        for (int n = 0; n < 4; ++n) {
          uint32_t kr = (uint32_t)(n * 16 + ln15);
          uint32_t off = (kr * 128u + (uint32_t)(kc * 64 + g * 16)) ^ ((kr & 7u) << 4);
          kf[n] = *(const bf16x8*)(kb + off);
        }
#pragma unroll
        for (int n = 0; n < 4; ++n) s_acc[n] = mfma16(kf[n], qf[kc], s_acc[n]);
      }
      __builtin_amdgcn_s_setprio(0);

      // causal mask on boundary tiles (wave-uniform test)
      if (s0 + 63 > r0) {
        const int qi = r0 + ln15;
#pragma unroll
        for (int n = 0; n < 4; ++n)
#pragma unroll
          for (int j = 0; j < 4; ++j) {
            int si = s0 + n * 16 + g * 4 + j;
            s_acc[n][j] = (si > qi) ? -1e30f : s_acc[n][j];
          }
      }

      // softmax: lane-local max tree (no shfl); rescale branch is rare.
      float mx;
      {
        float a0 = fmaxf(fmaxf(s_acc[0][0], s_acc[0][1]), s_acc[0][2]);
        float a1 = fmaxf(fmaxf(s_acc[0][3], s_acc[1][0]), s_acc[1][1]);
        float a2 = fmaxf(fmaxf(s_acc[1][2], s_acc[1][3]), s_acc[2][0]);
        float a3 = fmaxf(fmaxf(s_acc[2][1], s_acc[2][2]), s_acc[2][3]);
        float a4 = fmaxf(fmaxf(s_acc[3][0], s_acc[3][1]), s_acc[3][2]);
        float b0 = fmaxf(fmaxf(a0, a1), a2);
        float b1 = fmaxf(fmaxf(a3, a4), s_acc[3][3]);
        mx = fmaxf(b0, b1);
      }
      if (__any(mx > m_run + 8.0f)) {  // defer-max: P bounded by 2^8
        float mr = fmaxf(mx, __shfl_xor(mx, 16));
        mr = fmaxf(mr, __shfl_xor(mr, 32));     // row max, uniform across g
        float mn = fmaxf(m_run, mr);
        float al = fast_exp2(m_run - mn);       // row-uniform
        m_run = mn;
        l_run *= al;
#pragma unroll
        for (int j = 0; j < 4; ++j) {
          float aj = __shfl(al, g * 4 + j);  // alpha of q-row g*4+j
#pragma unroll
          for (int n = 0; n < 4; ++n) o_acc[n][j] *= aj;
        }
      }
      float ps = 0.f;
#pragma unroll
      for (int n = 0; n < 4; ++n) {
        float p0 = fast_exp2(s_acc[n][0] - m_run);
        float p1 = fast_exp2(s_acc[n][1] - m_run);
        float p2 = fast_exp2(s_acc[n][2] - m_run);
        float p3 = fast_exp2(s_acc[n][3] - m_run);
        ps += (p0 + p1) + (p2 + p3);
        bf16x4 pk = {(__bf16)p0, (__bf16)p1, (__bf16)p2, (__bf16)p3};
        // P[q=ln15][k=n*16+g*4 .. +3], row-swizzled like K/V
        uint32_t off = ((uint32_t)ln15 * 128u + (uint32_t)(n * 32 + g * 8)) ^
                       (((uint32_t)ln15 & 7u) << 4);
        *(bf16x4*)(lds + pbase + off) = pk;
      }
      l_run += ps;  // g-partial; reduced once in the epilogue

      // O += P V  (P wave-private)
      __builtin_amdgcn_s_setprio(1);
#pragma unroll
      for (int kc = 0; kc < 2; ++kc) {
        uint32_t poff = ((uint32_t)ln15 * 128u + (uint32_t)(kc * 64 + g * 16)) ^
                        (((uint32_t)ln15 & 7u) << 4);
        bf16x8 pf = *(const bf16x8*)(lds + pbase + poff);
        bf16x8 vf[4];
#pragma unroll
        for (int n = 0; n < 4; ++n) {
          uint32_t vr = (uint32_t)(n * 16 + ln15);
          uint32_t off = (vr * 128u + (uint32_t)(kc * 64 + g * 16)) ^ ((vr & 7u) << 4);
          vf[n] = *(const bf16x8*)(vb + off);
        }
#pragma unroll
        for (int n = 0; n < 4; ++n) o_acc[n] = mfma16(pf, vf[n], o_acc[n]);
      }
      __builtin_amdgcn_s_setprio(0);
    }
    cur ^= 1;  // single barrier per step: next iter's barrier covers reuse
  }

  // complete the deferred cross-g l reduction (butterfly over bits 4,5)
  l_run += __shfl_xor(l_run, 16);
  l_run += __shfl_xor(l_run, 32);

  // normalize and write final O (bf16) packed as (B*L, E)
  float invl = 1.0f / l_run;
#pragma unroll
  for (int j = 0; j < 4; ++j) {
    float inv = __shfl(invl, g * 4 + j);
    int qi = r0 + g * 4 + j;
    size_t rowo = ((size_t)b * NL + qi) * NE + h * ND;
#pragma unroll
    for (int n = 0; n < 4; ++n) Op[rowo + n * 16 + ln15] = f2bf(o_acc[n][j] * inv);
  }
}

// ---------------------------------------------------------------- out-proj + residual
// Double-buffered LDS, single barrier per K-step.
__global__ __launch_bounds__(256) void oproj_kernel(
    const ushort* __restrict__ ob, const ushort* __restrict__ wob,
    const float* __restrict__ bo, const float* __restrict__ x,
    float* __restrict__ out) {
  __shared__ __align__(128) char lds[65536];  // A dbuf 2x16K, B dbuf 2x16K
  const int tid = threadIdx.x;
  const int w = tid >> 6, ln = tid & 63;
  const int ln15 = ln & 15, g = ln >> 4;
  const int wm = w >> 1, wn = w & 1;
  const int m0 = blockIdx.y * 128;
  const int n0 = blockIdx.x * 128;

  const char* Abase = (const char*)ob + (size_t)m0 * 2048;
  const char* Bbase = (const char*)wob + (size_t)n0 * 2048;

  f32x4 acc[4][4];
#pragma unroll
  for (int m = 0; m < 4; ++m)
#pragma unroll
    for (int n = 0; n < 4; ++n) acc[m][n] = {0.f, 0.f, 0.f, 0.f};

  int cur = 0;
  stage_swz<4>(Abase, 2048, lds, tid);
  stage_swz<4>(Bbase, 2048, lds + 32768, tid);

  for (int kt = 0; kt < 16; ++kt) {
    asm volatile("s_waitcnt vmcnt(0)" ::: "memory");
    __builtin_amdgcn_s_barrier();
    asm volatile("" ::: "memory");
    if (kt + 1 < 16) {
      stage_swz<4>(Abase + (kt + 1) * 128, 2048, lds + (cur ^ 1) * 16384, tid);
      stage_swz<4>(Bbase + (kt + 1) * 128, 2048,
                   lds + 32768 + (cur ^ 1) * 16384, tid);
    }
    const char* ab = lds + cur * 16384;
    const char* bb = lds + 32768 + cur * 16384;
    __builtin_amdgcn_s_setprio(1);
#pragma unroll
    for (int kc = 0; kc < 2; ++kc) {
      bf16x8 af[4], bfr[4];
#pragma unroll
      for (int i = 0; i < 4; ++i) {
        uint32_t ar = (uint32_t)(wm * 64 + i * 16 + ln15);
        uint32_t ao = (ar * 128u + (uint32_t)(kc * 64 + g * 16)) ^ ((ar & 7u) << 4);
        af[i] = *(const bf16x8*)(ab + ao);
        uint32_t br = (uint32_t)(wn * 64 + i * 16 + ln15);
        uint32_t bo_ = (br * 128u + (uint32_t)(kc * 64 + g * 16)) ^ ((br & 7u) << 4);
        bfr[i] = *(const bf16x8*)(bb + bo_);
      }
#pragma unroll
      for (int m = 0; m < 4; ++m)
#pragma unroll
        for (int n = 0; n < 4; ++n) acc[m][n] = mfma16(af[m], bfr[n], acc[m][n]);
    }
    __builtin_amdgcn_s_setprio(0);
    cur ^= 1;
  }

#pragma unroll
  for (int n = 0; n < 4; ++n) {
    const int col = n0 + wn * 64 + n * 16 + ln15;
    const float bc = bo[col];
#pragma unroll
    for (int m = 0; m < 4; ++m)
#pragma unroll
      for (int j = 0; j < 4; ++j) {
        int mg = m0 + wm * 64 + m * 16 + g * 4 + j;
        size_t idx = (size_t)mg * NE + col;
        out[idx] = acc[m][n][j] + bc + x[idx];
      }
  }
}

// ---------------------------------------------------------------- LayerNorm (in-place)
__global__ __launch_bounds__(256) void ln_kernel(float* __restrict__ io,
                                                 const float* __restrict__ gamma,
                                                 const float* __restrict__ beta) {
  const int row = blockIdx.x, tid = threadIdx.x;
  const int w = tid >> 6, ln = tid & 63;
  float4 v = *(const float4*)(io + (size_t)row * NE + tid * 4);
  float s = v.x + v.y + v.z + v.w;
  float ss = v.x * v.x + v.y * v.y + v.z * v.z + v.w * v.w;
#pragma unroll
  for (int d = 1; d < 64; d <<= 1) {
    s += __shfl_xor(s, d);
    ss += __shfl_xor(ss, d);
  }
  __shared__ float red[8];
  if (ln == 0) {
    red[w] = s;
    red[4 + w] = ss;
  }
  __syncthreads();
  s = red[0] + red[1] + red[2] + red[3];
  ss = red[4] + red[5] + red[6] + red[7];
  const float mu = s * (1.0f / (float)NE);
  float var = ss * (1.0f / (float)NE) - mu * mu;
  const float inv = rsqrtf(var + 1e-5f);
  float4 gv = *(const float4*)(gamma + tid * 4);
  float4 bv = *(const float4*)(beta + tid * 4);
  float4 o;
  o.x = (v.x - mu) * inv * gv.x + bv.x;
  o.y = (v.y - mu) * inv * gv.y + bv.y;
  o.z = (v.z - mu) * inv * gv.z + bv.z;
  o.w = (v.w - mu) * inv * gv.w + bv.w;
  *(float4*)(io + (size_t)row * NE + tid * 4) = o;
}

// ---------------------------------------------------------------- launch
extern "C" void kernel_launch(void* const* d_in, const int* in_sizes, int n_in,
                              void* d_out, int out_size, void* d_ws, size_t ws_size,
                              hipStream_t stream) {
  const float* x = (const float*)d_in[0];
  // d_in[1] = mask (causal, recomputed analytically -> unused)
  const float* Wq = (const float*)d_in[2];
  const float* bq = (const float*)d_in[3];
  const float* Wk = (const float*)d_in[4];
  const float* bk = (const float*)d_in[5];
  const float* Wv = (const float*)d_in[6];
  const float* bv = (const float*)d_in[7];
  const float* Wo = (const float*)d_in[8];
  const float* bo = (const float*)d_in[9];
  const float* gamma = (const float*)d_in[10];
  const float* beta = (const float*)d_in[11];

  char* ws = (char*)d_ws;
  ushort* xb  = (ushort*)(ws + 0);          // 8 MB  (4096x1024 bf16)
  ushort* wqb = (ushort*)(ws + 8388608);    // 2 MB (wqb/wkb/wvb contiguous)
  ushort* wkb = (ushort*)(ws + 10485760);   // 2 MB (forms [3072][1024] bf16)
  ushort* wvb = (ushort*)(ws + 12582912);   // 2 MB
  ushort* wob = (ushort*)(ws + 14680064);   // 2 MB
  ushort* Qb  = (ushort*)(ws + 16777216);   // 8 MB (B,H,L,D) pre-scaled
  ushort* Kb  = (ushort*)(ws + 25165824);   // 8 MB (B,H,L,D)
  ushort* Vtb = (ushort*)(ws + 33554432);   // 8 MB (B,H,D,L)
  ushort* Ob  = (ushort*)(ws + 41943040);   // 8 MB (B*L, E)

  pack_kernel<<<8192, 256, 0, stream>>>(x, Wq, Wk, Wv, Wo, xb, wqb, wkb, wvb, wob);
  qkv_gemm_kernel<<<256, 512, 0, stream>>>(xb, wqb, bq, bk, bv, Qb, Kb, Vtb);
  attn_kernel<<<512, 512, 0, stream>>>(Qb, Kb, Vtb, Ob);
  oproj_kernel<<<dim3(8, 32), 256, 0, stream>>>(Ob, wob, bo, x, (float*)d_out);
  ln_kernel<<<4096, 256, 0, stream>>>((float*)d_out, gamma, beta);
}